// Round 1
// baseline (413.374 us; speedup 1.0000x reference)
//
#include <hip/hip_runtime.h>
#include <stdint.h>

// fp32 -> bf16(e8m7) round-to-nearest-even with saturation to bf16-max.
// Bit-exact vs the reference float_quantize(x, 8, 7):
//  - round(x/2^(e-7))*2^(e-7) with half-to-even == RNE truncation to 7 mantissa bits
//  - reference's floor(log2) fp32 boundary cases coincide with RNE carry-out, same result
//  - clip to (2-2^-7)*2^127 == saturate instead of overflowing to inf
//  - subnormals: truncation to top-16 bits == round to multiples of 2^-133 (scale at e=-126)
__device__ __forceinline__ float bf16_rne(float x) {
    uint32_t u = __float_as_uint(x);
    uint32_t r = (u + 0x7FFFu + ((u >> 16) & 1u)) & 0xFFFF0000u;
    if ((r & 0x7F800000u) == 0x7F800000u)            // overflow -> saturate (inputs are finite)
        r = (r & 0x80000000u) | 0x7F7F0000u;         // +/- bf16 max
    return __uint_as_float(r);
}

// One thread owns 4 consecutive elements (float4); an 8-element BFP block is an
// even/odd lane pair -> block max shared via one __shfl_xor over lane^1.
__global__ __launch_bounds__(256) void bfp_quant_kernel(const float4* __restrict__ in,
                                                        float4* __restrict__ out,
                                                        int n4) {
    int t = blockIdx.x * blockDim.x + threadIdx.x;
    if (t >= n4) return;

    float4 a = in[t];
    float v0 = bf16_rne(a.x);
    float v1 = bf16_rne(a.y);
    float v2 = bf16_rne(a.z);
    float v3 = bf16_rne(a.w);

    float m = fmaxf(fmaxf(fabsf(v0), fabsf(v1)), fmaxf(fabsf(v2), fabsf(v3)));
    m = fmaxf(m, __shfl_xor(m, 1));   // max over the 8-element block (lane pair)

    float4 o;
    if (m > 0.0f) {
        // m is an exact bf16 magnitude (normal for this data): floor(log2(m)) == exponent field
        int E = (int)((__float_as_uint(m) >> 23) & 0xFFu) - 127;
        int s_up = 6 - E;   // x / 2^(E-6)
        int s_dn = E - 6;
        float q0 = fminf(fmaxf(rintf(ldexpf(v0, s_up)), -127.0f), 127.0f);
        float q1 = fminf(fmaxf(rintf(ldexpf(v1, s_up)), -127.0f), 127.0f);
        float q2 = fminf(fmaxf(rintf(ldexpf(v2, s_up)), -127.0f), 127.0f);
        float q3 = fminf(fmaxf(rintf(ldexpf(v3, s_up)), -127.0f), 127.0f);
        o.x = ldexpf(q0, s_dn);
        o.y = ldexpf(q1, s_dn);
        o.z = ldexpf(q2, s_dn);
        o.w = ldexpf(q3, s_dn);
    } else {
        o = make_float4(0.0f, 0.0f, 0.0f, 0.0f);
    }
    out[t] = o;
}

extern "C" void kernel_launch(void* const* d_in, const int* in_sizes, int n_in,
                              void* d_out, int out_size, void* d_ws, size_t ws_size,
                              hipStream_t stream) {
    const float* x = (const float*)d_in[0];
    float* out = (float*)d_out;
    int n = in_sizes[0];          // 8*2048*4096 = 67,108,864 (divisible by 8)
    int n4 = n >> 2;              // float4 groups
    int block = 256;
    int grid = (n4 + block - 1) / block;
    bfp_quant_kernel<<<grid, block, 0, stream>>>((const float4*)x, (float4*)out, n4);
}